// Round 1
// baseline (1804.353 us; speedup 1.0000x reference)
//
#include <hip/hip_runtime.h>

// Problem dims
static constexpr int B_ = 32, C_ = 256, K_ = 64, H_ = 64, W_ = 64;
static constexpr int N_ = H_ * W_;      // 4096
static constexpr int IN_ = C_ + K_;     // 320

// Workspace layout (in floats). px reuses corr+dws region (dead by then).
static constexpr long long OFF_S    = 0;                        // B*C*N = 33,554,432
static constexpr long long OFF_CORR = 33554432LL;               // B*K*N = 8,388,608
static constexpr long long OFF_DWS  = OFF_CORR + 8388608LL;     // B*IN*N = 41,943,040
static constexpr long long OFF_PX   = OFF_CORR;                 // reuse (134MB <= 201MB)
static constexpr long long OFF_SM   = OFF_DWS + 41943040LL;
static constexpr long long OFF_G    = OFF_SM;                   // B*C*C = 2,097,152
static constexpr long long OFF_T1   = OFF_G   + 2097152LL;
static constexpr long long OFF_ATT  = OFF_T1  + 2097152LL;
static constexpr long long OFF_M2   = OFF_ATT + 2097152LL;
static constexpr long long OFF_M3   = OFF_M2  + 2097152LL;
static constexpr long long OFF_R    = OFF_M3  + 2097152LL;      // B*C
static constexpr long long OFF_U    = OFF_R   + 8192LL;
static constexpr long long OFF_W2   = OFF_U   + 8192LL;
static constexpr long long OFF_M2B  = OFF_W2  + 8192LL;
static constexpr long long OFF_B3   = OFF_M2B + 8192LL;
static constexpr long long OFF_BNS  = OFF_B3  + 8192LL;         // C
static constexpr long long OFF_BNH  = OFF_BNS + 256LL;          // C
// total = 94,413,312 floats = 377.6 MB

// ---------------------------------------------------------------------------
// Generic 64x64 tiled fp32 GEMM, 256 threads, 4x4 per thread, BK=16.
// TA=0: A is [M,K] row-major (lda=K-stride). TA=1: A is [K,M] (lda=M-stride).
// TB=0: B is [K,N]. TB=1: B is [N,K].
// EPI bits: 1=+bias[row] (per-batch stride sBias), 2=BN+ReLU (scl/shf per row),
//           4=+resid[b,row,col], 8=*alpha
// All dims must divide the tile exactly (true for every call here).
// ---------------------------------------------------------------------------
template <int TA, int TB, int EPI>
__global__ __launch_bounds__(256) void gemm64(
    const float* __restrict__ A, int lda, long long sA,
    const float* __restrict__ B, int ldb, long long sB,
    float* __restrict__ Cout, int ldc, long long sC,
    int Kd,
    const float* __restrict__ bias, int sBias,
    const float* __restrict__ scl, const float* __restrict__ shf,
    const float* __restrict__ resid, int ldr, long long sR,
    float alpha)
{
  const int n0 = blockIdx.x * 64;
  const int m0 = blockIdx.y * 64;
  const int bz = blockIdx.z;
  A += (long long)bz * sA;
  B += (long long)bz * sB;
  Cout += (long long)bz * sC;

  __shared__ __align__(16) float As[16][68];  // [k][m], pad 68 -> 2-way max
  __shared__ __align__(16) float Bs[16][68];  // [k][n]

  const int tid = threadIdx.x;
  const int tx = tid & 15, ty = tid >> 4;

  float acc[4][4] = {{0.f, 0.f, 0.f, 0.f}, {0.f, 0.f, 0.f, 0.f},
                     {0.f, 0.f, 0.f, 0.f}, {0.f, 0.f, 0.f, 0.f}};

  for (int k0 = 0; k0 < Kd; k0 += 16) {
    if (TA == 0) {
      const int m = tid >> 2, k4 = (tid & 3) << 2;
      float4 v = *(const float4*)(A + (long long)(m0 + m) * lda + k0 + k4);
      As[k4 + 0][m] = v.x; As[k4 + 1][m] = v.y;
      As[k4 + 2][m] = v.z; As[k4 + 3][m] = v.w;
    } else {
      const int kk = tid >> 4, m4 = (tid & 15) << 2;
      *(float4*)&As[kk][m4] =
          *(const float4*)(A + (long long)(k0 + kk) * lda + m0 + m4);
    }
    if (TB == 0) {
      const int kk = tid >> 4, n4 = (tid & 15) << 2;
      *(float4*)&Bs[kk][n4] =
          *(const float4*)(B + (long long)(k0 + kk) * ldb + n0 + n4);
    } else {
      const int n = tid >> 2, k4 = (tid & 3) << 2;
      float4 v = *(const float4*)(B + (long long)(n0 + n) * ldb + k0 + k4);
      Bs[k4 + 0][n] = v.x; Bs[k4 + 1][n] = v.y;
      Bs[k4 + 2][n] = v.z; Bs[k4 + 3][n] = v.w;
    }
    __syncthreads();
#pragma unroll
    for (int kk = 0; kk < 16; ++kk) {
      float4 av = *(const float4*)&As[kk][ty << 2];
      float4 bv = *(const float4*)&Bs[kk][tx << 2];
      float a[4] = {av.x, av.y, av.z, av.w};
      float b[4] = {bv.x, bv.y, bv.z, bv.w};
#pragma unroll
      for (int i = 0; i < 4; ++i)
#pragma unroll
        for (int j = 0; j < 4; ++j)
          acc[i][j] = fmaf(a[i], b[j], acc[i][j]);
    }
    __syncthreads();
  }

#pragma unroll
  for (int i = 0; i < 4; ++i) {
    const int row = m0 + (ty << 2) + i;
#pragma unroll
    for (int j = 0; j < 4; ++j) {
      const int col = n0 + (tx << 2) + j;
      float v = acc[i][j];
      if (EPI & 8) v *= alpha;
      if (EPI & 1) v += bias[bz * sBias + row];
      if (EPI & 2) v = fmaxf(fmaf(v, scl[row], shf[row]), 0.f);
      if (EPI & 4) v += resid[(long long)bz * sR + (long long)row * ldr + col];
      Cout[(long long)row * ldc + col] = v;
    }
  }
}

// Fold BN(+pw bias) into per-channel scale/shift: y = relu(x*scl + shf)
__global__ void bncoef(const float* __restrict__ pwb, const float* __restrict__ g,
                       const float* __restrict__ bt, const float* __restrict__ mn,
                       const float* __restrict__ vr, float* __restrict__ scl,
                       float* __restrict__ shf)
{
  const int c = threadIdx.x;
  const float inv = rsqrtf(vr[c] + 1e-5f);
  const float sc = g[c] * inv;
  scl[c] = sc;
  shf[c] = (pwb[c] - mn[c]) * sc + bt[c];
}

// Depthwise 3x3, pad=1, over concat([corr(64ch), d(256ch)])
__global__ void dwconv(const float* __restrict__ corr, const float* __restrict__ dimg,
                       const float* __restrict__ wgt, const float* __restrict__ bias,
                       float* __restrict__ outp)
{
  const int x = threadIdx.x;                         // 0..63
  const int y = blockIdx.x * 4 + threadIdx.y;        // 0..63
  const int ch = blockIdx.y;                         // 0..319
  const int b = blockIdx.z;
  const float* in = (ch < K_)
      ? corr + ((long long)b * K_ + ch) * (long long)N_
      : dimg + ((long long)b * C_ + (ch - K_)) * (long long)N_;
  float wv[9];
#pragma unroll
  for (int i = 0; i < 9; ++i) wv[i] = wgt[ch * 9 + i];
  float acc = bias[ch];
#pragma unroll
  for (int dy = -1; dy <= 1; ++dy) {
    const int yy = y + dy;
    if (yy < 0 || yy >= H_) continue;
#pragma unroll
    for (int dx = -1; dx <= 1; ++dx) {
      const int xx = x + dx;
      if (xx < 0 || xx >= W_) continue;
      acc = fmaf(wv[(dy + 1) * 3 + (dx + 1)], in[yy * W_ + xx], acc);
    }
  }
  outp[((long long)b * IN_ + ch) * (long long)N_ + y * W_ + x] = acc;
}

// r[b,c] = sum_n px[b,c,n]
__global__ void rowsum(const float* __restrict__ px, float* __restrict__ r)
{
  const int c = blockIdx.x, b = blockIdx.y, t = threadIdx.x;
  const float* p = px + ((long long)b * C_ + c) * (long long)N_;
  float s = 0.f;
  for (int i = t; i < N_; i += 256) s += p[i];
  __shared__ float red[256];
  red[t] = s;
  __syncthreads();
  for (int k = 128; k > 0; k >>= 1) {
    if (t < k) red[t] += red[t + k];
    __syncthreads();
  }
  if (t == 0) r[b * C_ + c] = red[0];
}

// u = q_w @ r, w = k_w @ r   (per batch)
__global__ void uwker(const float* __restrict__ qw, const float* __restrict__ kw,
                      const float* __restrict__ r, float* __restrict__ u,
                      float* __restrict__ w)
{
  const int b = blockIdx.x, c = threadIdx.x;
  __shared__ float rl[256];
  rl[c] = r[b * C_ + c];
  __syncthreads();
  float su = 0.f, sw = 0.f;
  for (int f = 0; f < C_; ++f) {
    const float rv = rl[f];
    su = fmaf(qw[c * C_ + f], rv, su);
    sw = fmaf(kw[c * C_ + f], rv, sw);
  }
  u[b * C_ + c] = su;
  w[b * C_ + c] = sw;
}

// score += (1/16)*(u[c]*k_b[d] + q_b[c]*w[d] + N*q_b[c]*k_b[d]); softmax over d
__global__ void fixsoftmax(float* __restrict__ att, const float* __restrict__ u,
                           const float* __restrict__ w, const float* __restrict__ qb,
                           const float* __restrict__ kb)
{
  const int c = blockIdx.x, b = blockIdx.y, d = threadIdx.x;
  const long long base = ((long long)b * C_ + c) * (long long)C_;
  const float qbc = qb[c];
  float val = att[base + d] +
              0.0625f * (u[b * C_ + c] * kb[d] + qbc * w[b * C_ + d] +
                         (float)N_ * qbc * kb[d]);
  __shared__ float red[256];
  red[d] = val;
  __syncthreads();
  for (int k = 128; k > 0; k >>= 1) {
    if (d < k) red[d] = fmaxf(red[d], red[d + k]);
    __syncthreads();
  }
  const float mx = red[0];
  __syncthreads();
  const float e = expf(val - mx);
  red[d] = e;
  __syncthreads();
  for (int k = 128; k > 0; k >>= 1) {
    if (d < k) red[d] += red[d + k];
    __syncthreads();
  }
  att[base + d] = e / red[0];
}

// m2b[b,d] = sum_c att[b,c,d] * v_b[c]
__global__ void m2bker(const float* __restrict__ att, const float* __restrict__ vb,
                       float* __restrict__ m2b)
{
  const int b = blockIdx.x, d = threadIdx.x;
  const float* a = att + (long long)b * C_ * C_;
  float s = 0.f;
  for (int c = 0; c < C_; ++c) s = fmaf(a[c * C_ + d], vb[c], s);
  m2b[b * C_ + d] = s;
}

// bias3[b,o] = sum_d op_w[o,d]*m2b[b,d] + op_b[o]
__global__ void b3ker(const float* __restrict__ opw, const float* __restrict__ m2b,
                      const float* __restrict__ opb, float* __restrict__ b3)
{
  const int b = blockIdx.x, o = threadIdx.x;
  __shared__ float m[256];
  m[o] = m2b[b * C_ + o];
  __syncthreads();
  float s = opb[o];
  for (int d = 0; d < C_; ++d) s = fmaf(opw[o * C_ + d], m[d], s);
  b3[b * C_ + o] = s;
}

extern "C" void kernel_launch(void* const* d_in, const int* in_sizes, int n_in,
                              void* d_out, int out_size, void* d_ws, size_t ws_size,
                              hipStream_t stream)
{
  (void)in_sizes; (void)n_in; (void)out_size; (void)ws_size;
  const float* z     = (const float*)d_in[0];
  const float* x     = (const float*)d_in[1];
  const float* dimg  = (const float*)d_in[2];
  const float* dw_w  = (const float*)d_in[3];
  const float* dw_b  = (const float*)d_in[4];
  const float* pw_w  = (const float*)d_in[5];
  const float* pw_b  = (const float*)d_in[6];
  const float* bn_g  = (const float*)d_in[7];
  const float* bn_b  = (const float*)d_in[8];
  const float* bn_m  = (const float*)d_in[9];
  const float* bn_v  = (const float*)d_in[10];
  const float* inp_w = (const float*)d_in[11];
  const float* inp_b = (const float*)d_in[12];
  const float* q_w   = (const float*)d_in[13];
  const float* q_b   = (const float*)d_in[14];
  const float* k_w   = (const float*)d_in[15];
  const float* k_b   = (const float*)d_in[16];
  const float* v_w   = (const float*)d_in[17];
  const float* v_b   = (const float*)d_in[18];
  const float* op_w  = (const float*)d_in[19];
  const float* op_b  = (const float*)d_in[20];
  float* out = (float*)d_out;

  float* wsf  = (float*)d_ws;
  float* s    = wsf + OFF_S;
  float* corr = wsf + OFF_CORR;
  float* dws  = wsf + OFF_DWS;
  float* px   = wsf + OFF_PX;
  float* G    = wsf + OFF_G;
  float* T1   = wsf + OFF_T1;
  float* att  = wsf + OFF_ATT;
  float* M2   = wsf + OFF_M2;
  float* M3   = wsf + OFF_M3;
  float* r    = wsf + OFF_R;
  float* u    = wsf + OFF_U;
  float* w2   = wsf + OFF_W2;
  float* m2b  = wsf + OFF_M2B;
  float* b3   = wsf + OFF_B3;
  float* bns  = wsf + OFF_BNS;
  float* bnh  = wsf + OFF_BNH;

  const long long sCN = (long long)C_ * N_;   // 1,048,576
  const long long sKN = (long long)K_ * N_;
  const long long sIN = (long long)IN_ * N_;
  const long long sCC = (long long)C_ * C_;

  // BN fold
  bncoef<<<1, 256, 0, stream>>>(pw_b, bn_g, bn_b, bn_m, bn_v, bns, bnh);

  // corr[b,k,n] = sum_c z[b,c,k] x[b,c,n]   (TA=1: A=[K?,..] = z [C,K], TB=0: x [C,N])
  gemm64<1, 0, 0><<<dim3(N_ / 64, K_ / 64, B_), 256, 0, stream>>>(
      z, K_, (long long)C_ * K_, x, N_, sCN, corr, N_, sKN, C_,
      nullptr, 0, nullptr, nullptr, nullptr, 0, 0, 1.f);

  // depthwise 3x3 over concat([corr, d])
  dwconv<<<dim3(H_ / 4, IN_, B_), dim3(64, 4), 0, stream>>>(corr, dimg, dw_w, dw_b, dws);

  // s = relu(BN(pw_w @ dws + pw_b))
  gemm64<0, 0, 2><<<dim3(N_ / 64, C_ / 64, B_), 256, 0, stream>>>(
      pw_w, IN_, 0, dws, N_, sIN, s, N_, sCN, IN_,
      nullptr, 0, bns, bnh, nullptr, 0, 0, 1.f);

  // px = inp_w @ s + inp_b
  gemm64<0, 0, 1><<<dim3(N_ / 64, C_ / 64, B_), 256, 0, stream>>>(
      inp_w, C_, 0, s, N_, sCN, px, N_, sCN, C_,
      inp_b, 0, nullptr, nullptr, nullptr, 0, 0, 1.f);

  // r = row sums of px
  rowsum<<<dim3(C_, B_), 256, 0, stream>>>(px, r);

  // G = px @ px^T  (K = 4096)
  gemm64<0, 1, 0><<<dim3(C_ / 64, C_ / 64, B_), 256, 0, stream>>>(
      px, N_, sCN, px, N_, sCN, G, C_, sCC, N_,
      nullptr, 0, nullptr, nullptr, nullptr, 0, 0, 1.f);

  // u = q_w r, w2 = k_w r
  uwker<<<B_, 256, 0, stream>>>(q_w, k_w, r, u, w2);

  // T1 = q_w @ G
  gemm64<0, 0, 0><<<dim3(C_ / 64, C_ / 64, B_), 256, 0, stream>>>(
      q_w, C_, 0, G, C_, sCC, T1, C_, sCC, C_,
      nullptr, 0, nullptr, nullptr, nullptr, 0, 0, 1.f);

  // score = (1/16) T1 @ k_w^T   -> att buffer
  gemm64<0, 1, 8><<<dim3(C_ / 64, C_ / 64, B_), 256, 0, stream>>>(
      T1, C_, sCC, k_w, C_, 0, att, C_, sCC, C_,
      nullptr, 0, nullptr, nullptr, nullptr, 0, 0, 0.0625f);

  // rank-1 bias fix + softmax over d (in place)
  fixsoftmax<<<dim3(C_, B_), 256, 0, stream>>>(att, u, w2, q_b, k_b);

  // M2 = att^T @ v_w   (TA=1: att [C,C] c-major)
  gemm64<1, 0, 0><<<dim3(C_ / 64, C_ / 64, B_), 256, 0, stream>>>(
      att, C_, sCC, v_w, C_, 0, M2, C_, sCC, C_,
      nullptr, 0, nullptr, nullptr, nullptr, 0, 0, 1.f);

  // m2b = att^T v_b
  m2bker<<<B_, 256, 0, stream>>>(att, v_b, m2b);

  // M3 = op_w @ M2
  gemm64<0, 0, 0><<<dim3(C_ / 64, C_ / 64, B_), 256, 0, stream>>>(
      op_w, C_, 0, M2, C_, sCC, M3, C_, sCC, C_,
      nullptr, 0, nullptr, nullptr, nullptr, 0, 0, 1.f);

  // bias3 = op_w m2b + op_b
  b3ker<<<B_, 256, 0, stream>>>(op_w, m2b, op_b, b3);

  // out = M3 @ px + bias3 + s
  gemm64<0, 0, 5><<<dim3(N_ / 64, C_ / 64, B_), 256, 0, stream>>>(
      M3, C_, sCC, px, N_, sCN, out, N_, sCN, C_,
      b3, C_, nullptr, nullptr, s, N_, sCN, 1.f);
}

// Round 2
// 1117.233 us; speedup vs baseline: 1.6150x; 1.6150x over previous
//
#include <hip/hip_runtime.h>

static constexpr int B_ = 32, C_ = 256, K_ = 64, H_ = 64, W_ = 64;
static constexpr int N_ = H_ * W_;      // 4096
static constexpr int IN_ = C_ + K_;     // 320

// ---------------- bf16 helpers (raw short storage) ----------------
__device__ __forceinline__ short f2bs(float f) {
  unsigned u = __builtin_bit_cast(unsigned, f);
  u += 0x7fffu + ((u >> 16) & 1u);
  return (short)(u >> 16);
}
__device__ __forceinline__ float bs2f(short s) {
  unsigned u = ((unsigned)(unsigned short)s) << 16;
  return __builtin_bit_cast(float, u);
}

typedef __attribute__((ext_vector_type(8))) short s8v;
typedef __attribute__((ext_vector_type(4))) short s4v;
typedef __attribute__((ext_vector_type(4))) float f4v;

// ---------------- workspace layout (bytes) ----------------
// R1 [0,80MB): xt(64MB)+zt(1MB), later reused for dws(80MB)
// R2 [80,144MB): dt, later px_b
// R3 [144,160MB): corr_b(16MB), later G(8MB)+T1(8MB)
// R4 [160,224MB): s_b
// R5 [224,288MB): pxT_b
// R6 [288,312MB): att, M2, M3 (fp32, 8MB each)
// R7 [312MB..): small buffers
static constexpr long long OB_XT   = 0;
static constexpr long long OB_ZT   = 67108864LL;
static constexpr long long OB_DWS  = 0;
static constexpr long long OB_DT   = 83886080LL;
static constexpr long long OB_PX   = 83886080LL;
static constexpr long long OB_CORR = 150994944LL;
static constexpr long long OB_G    = 150994944LL;
static constexpr long long OB_T1   = 159383552LL;
static constexpr long long OB_S    = 167772160LL;
static constexpr long long OB_PXT  = 234881024LL;
static constexpr long long OB_ATT  = 301989888LL;
static constexpr long long OB_M2   = OB_ATT + 8388608LL;
static constexpr long long OB_M3   = OB_M2 + 8388608LL;
static constexpr long long OB_MISC = OB_M3 + 8388608LL;          // 318.8MB
static constexpr long long OB_PWW  = OB_MISC;                    // 320*256*2
static constexpr long long OB_INPW = OB_PWW + 262144LL;
static constexpr long long OB_M3B  = OB_INPW + 262144LL;         // 4MB bf16
static constexpr long long OB_R    = OB_M3B + 4194304LL;         // fp32 vecs
static constexpr long long OB_U    = OB_R + 32768LL;
static constexpr long long OB_W2   = OB_U + 32768LL;
static constexpr long long OB_M2B  = OB_W2 + 32768LL;
static constexpr long long OB_B3   = OB_M2B + 32768LL;
static constexpr long long OB_BNS  = OB_B3 + 32768LL;
static constexpr long long OB_BNH  = OB_BNS + 2048LL;
// total ~324MB (< 378MB verified available in round 1)

// ---------------- async global->LDS ----------------
__device__ __forceinline__ void gload16(const void* g, void* l) {
  __builtin_amdgcn_global_load_lds((const __attribute__((address_space(1))) void*)g,
                                   (__attribute__((address_space(3))) void*)l, 16, 0, 0);
}

// ===========================================================================
// MFMA bf16 GEMM: D[m,n] = sum_k A[m,k] * Bt[n,k]
// Tile 128 x BN, BK=32, 256 threads = 4 waves (2x2), 16x16x32 MFMA.
// EPI bits: 1=out bf16, 2=+biasc[n], 4=relu(v*biasc[n]+shf[n]), 8=+biasr[bz*256+m],
//           16=+resT[n*ldrt+m] (bf16), 32=also write bf16 outT[n*ldt+m], 64=atomicAdd f32
// ===========================================================================
template <int BN, int SPLIT, int EPI>
__global__ __launch_bounds__(256) void mgemm(
    const short* __restrict__ A, int lda, long long sA,
    const short* __restrict__ Bt, int ldb, long long sB,
    void* __restrict__ Cv, int ldc, long long sC,
    int Kd,
    const float* __restrict__ biasc, const float* __restrict__ shf,
    const float* __restrict__ biasr,
    const short* __restrict__ resT, int ldrt, long long sRT,
    short* __restrict__ outT, int ldt, long long sT)
{
  constexpr int JT = BN / 32;         // MFMA n-tiles per wave
  __shared__ short As[128 * 32];
  __shared__ short Bs[BN * 32];

  const int t = threadIdx.x;
  const int wv = t >> 6;
  const int lane = t & 63, quad = lane >> 4, lr = lane & 15;
  const int wm = wv >> 1, wn = wv & 1;
  const int m_off = wm * 64, n_off = wn * (BN / 2);

  const int n0 = blockIdx.x * BN;
  const int m0 = blockIdx.y * 128;
  const int bz = (SPLIT == 1) ? blockIdx.z : (blockIdx.z / SPLIT);
  const int sp = (SPLIT == 1) ? 0 : (blockIdx.z % SPLIT);
  const int koff = sp * Kd;

  A += (long long)bz * sA;
  Bt += (long long)bz * sB;

  const int arow = t >> 2;            // 0..63
  const int acol = (t & 3) << 3;      // element offset (8 shorts = 16B)

  f4v acc[4][JT];
#pragma unroll
  for (int i = 0; i < 4; ++i)
#pragma unroll
    for (int j = 0; j < JT; ++j) acc[i][j] = (f4v)0.f;

  for (int k0 = 0; k0 < Kd; k0 += 32) {
    // stage A tile: 128x32 bf16 = 8KB, two 4KB rounds
#pragma unroll
    for (int rr = 0; rr < 2; ++rr) {
      const short* gp = A + (long long)(m0 + rr * 64 + arow) * lda + koff + k0 + acol;
      gload16(gp, (char*)As + rr * 4096 + wv * 1024);
    }
    // stage Bt tile: BNx32
#pragma unroll
    for (int rr = 0; rr < BN / 64; ++rr) {
      const short* gp = Bt + (long long)(n0 + rr * 64 + arow) * ldb + koff + k0 + acol;
      gload16(gp, (char*)Bs + rr * 4096 + wv * 1024);
    }
    __syncthreads();

    s8v af[4], bfv[JT];
#pragma unroll
    for (int i = 0; i < 4; ++i)
      af[i] = *(const s8v*)&As[(m_off + i * 16 + lr) * 32 + quad * 8];
#pragma unroll
    for (int j = 0; j < JT; ++j)
      bfv[j] = *(const s8v*)&Bs[(n_off + j * 16 + lr) * 32 + quad * 8];
#pragma unroll
    for (int i = 0; i < 4; ++i)
#pragma unroll
      for (int j = 0; j < JT; ++j)
        acc[i][j] = __builtin_amdgcn_mfma_f32_16x16x32_bf16(af[i], bfv[j], acc[i][j], 0, 0, 0);
    __syncthreads();
  }

  // epilogue
  float* Cf = (float*)Cv;
  short* Cb = (short*)Cv;
  if (EPI & 1) Cb += (long long)bz * sC; else Cf += (long long)bz * sC;
  if (EPI & 16) resT += (long long)bz * sRT;
  if (EPI & 32) outT += (long long)bz * sT;

#pragma unroll
  for (int i = 0; i < 4; ++i) {
    const int mb = m0 + m_off + i * 16 + quad * 4;
#pragma unroll
    for (int j = 0; j < JT; ++j) {
      const int n = n0 + n_off + j * 16 + lr;
      float vr[4];
#pragma unroll
      for (int r = 0; r < 4; ++r) {
        float v = acc[i][j][r];
        if (EPI & 2) v += biasc[n];
        if (EPI & 4) v = fmaxf(fmaf(v, biasc[n], shf[n]), 0.f);
        if (EPI & 8) v += biasr[bz * 256 + mb + r];
        vr[r] = v;
      }
      if (EPI & 16) {
        s4v rv = *(const s4v*)(resT + (long long)n * ldrt + mb);
#pragma unroll
        for (int r = 0; r < 4; ++r) vr[r] += bs2f(rv[r]);
      }
      if (EPI & 32) {
        s4v tv;
#pragma unroll
        for (int r = 0; r < 4; ++r) tv[r] = f2bs(vr[r]);
        *(s4v*)(outT + (long long)n * ldt + mb) = tv;
      }
#pragma unroll
      for (int r = 0; r < 4; ++r) {
        if (EPI & 64) atomicAdd(&Cf[(long long)(mb + r) * ldc + n], vr[r]);
        else if (EPI & 1) Cb[(long long)(mb + r) * ldc + n] = f2bs(vr[r]);
        else Cf[(long long)(mb + r) * ldc + n] = vr[r];
      }
    }
  }
}

// ---------------- transpose-cast: in fp32 [R, Cc] -> out bf16 [Cc, R] ----------------
__global__ __launch_bounds__(256) void tcast(const float* __restrict__ in,
                                             short* __restrict__ out,
                                             int R, int Cc, long long sIn, long long sOut)
{
  __shared__ float tile[32][33];
  const int b = blockIdx.z;
  const int r0 = blockIdx.y * 32, c0 = blockIdx.x * 32;
  in += (long long)b * sIn;
  out += (long long)b * sOut;
  const int tx = threadIdx.x & 31, ty = threadIdx.x >> 5;   // ty 0..7
#pragma unroll
  for (int i = 0; i < 32; i += 8)
    tile[ty + i][tx] = in[(long long)(r0 + ty + i) * Cc + c0 + tx];
  __syncthreads();
#pragma unroll
  for (int i = 0; i < 32; i += 8)
    out[(long long)(c0 + ty + i) * R + r0 + tx] = f2bs(tile[tx][ty + i]);
}

// ---------------- flat fp32 -> bf16 cast ----------------
__global__ void castw(const float* __restrict__ in, short* __restrict__ out, long long n)
{
  long long i = (long long)blockIdx.x * 256 + threadIdx.x;
  if (i < n) out[i] = f2bs(in[i]);
}

// ---------------- depthwise 3x3 over concat([corr(64), d(256)]), [N,ch] layout ----------------
__global__ __launch_bounds__(320) void dwconv2(const short* __restrict__ corr,
                                               const short* __restrict__ dt,
                                               const float* __restrict__ wgt,
                                               const float* __restrict__ bias,
                                               short* __restrict__ outp)
{
  const int ch = threadIdx.x;          // 0..319
  const int n = blockIdx.x;            // 0..4095
  const int b = blockIdx.y;
  const int y = n >> 6, x = n & 63;
  const short* base;
  int ldch, cl;
  if (ch < K_) { base = corr + (long long)b * N_ * K_; ldch = K_; cl = ch; }
  else         { base = dt   + (long long)b * N_ * C_; ldch = C_; cl = ch - K_; }
  const float* wv = wgt + ch * 9;
  float acc = bias[ch];
#pragma unroll
  for (int dy = -1; dy <= 1; ++dy) {
    const int yy = y + dy;
    if (yy < 0 || yy >= H_) continue;
#pragma unroll
    for (int dx = -1; dx <= 1; ++dx) {
      const int xx = x + dx;
      if (xx < 0 || xx >= W_) continue;
      acc = fmaf(wv[(dy + 1) * 3 + (dx + 1)],
                 bs2f(base[(long long)(yy * W_ + xx) * ldch + cl]), acc);
    }
  }
  outp[((long long)b * N_ + n) * IN_ + ch] = f2bs(acc);
}

// ---------------- column sums of px_b [N, C] -> r[b, c] (atomic) ----------------
__global__ void colsum(const short* __restrict__ px, float* __restrict__ r)
{
  const int b = blockIdx.y, c = threadIdx.x, chunk = blockIdx.x;
  const short* p = px + (long long)b * N_ * C_ + (long long)chunk * 512 * C_;
  float s = 0.f;
  for (int n = 0; n < 512; ++n) s += bs2f(p[(long long)n * C_ + c]);
  atomicAdd(&r[b * C_ + c], s);
}

// ===========================================================================
// fp32 64x64 tiled GEMM for the small C x C products (unchanged from R1)
// ===========================================================================
template <int TA, int TB, int EPI>
__global__ __launch_bounds__(256) void gemm64(
    const float* __restrict__ A, int lda, long long sA,
    const float* __restrict__ B, int ldb, long long sB,
    float* __restrict__ Cout, int ldc, long long sC,
    int Kd, float alpha)
{
  const int n0 = blockIdx.x * 64;
  const int m0 = blockIdx.y * 64;
  const int bz = blockIdx.z;
  A += (long long)bz * sA;
  B += (long long)bz * sB;
  Cout += (long long)bz * sC;

  __shared__ __align__(16) float As[16][68];
  __shared__ __align__(16) float Bs[16][68];
  const int tid = threadIdx.x;
  const int tx = tid & 15, ty = tid >> 4;
  float acc[4][4] = {};

  for (int k0 = 0; k0 < Kd; k0 += 16) {
    if (TA == 0) {
      const int m = tid >> 2, k4 = (tid & 3) << 2;
      float4 v = *(const float4*)(A + (long long)(m0 + m) * lda + k0 + k4);
      As[k4 + 0][m] = v.x; As[k4 + 1][m] = v.y;
      As[k4 + 2][m] = v.z; As[k4 + 3][m] = v.w;
    } else {
      const int kk = tid >> 4, m4 = (tid & 15) << 2;
      *(float4*)&As[kk][m4] = *(const float4*)(A + (long long)(k0 + kk) * lda + m0 + m4);
    }
    if (TB == 0) {
      const int kk = tid >> 4, n4 = (tid & 15) << 2;
      *(float4*)&Bs[kk][n4] = *(const float4*)(B + (long long)(k0 + kk) * ldb + n0 + n4);
    } else {
      const int n = tid >> 2, k4 = (tid & 3) << 2;
      float4 v = *(const float4*)(B + (long long)(n0 + n) * ldb + k0 + k4);
      Bs[k4 + 0][n] = v.x; Bs[k4 + 1][n] = v.y;
      Bs[k4 + 2][n] = v.z; Bs[k4 + 3][n] = v.w;
    }
    __syncthreads();
#pragma unroll
    for (int kk = 0; kk < 16; ++kk) {
      float4 av = *(const float4*)&As[kk][ty << 2];
      float4 bv = *(const float4*)&Bs[kk][tx << 2];
      float a[4] = {av.x, av.y, av.z, av.w};
      float b[4] = {bv.x, bv.y, bv.z, bv.w};
#pragma unroll
      for (int i = 0; i < 4; ++i)
#pragma unroll
        for (int j = 0; j < 4; ++j) acc[i][j] = fmaf(a[i], b[j], acc[i][j]);
    }
    __syncthreads();
  }
#pragma unroll
  for (int i = 0; i < 4; ++i)
#pragma unroll
    for (int j = 0; j < 4; ++j) {
      float v = acc[i][j];
      if (EPI & 8) v *= alpha;
      Cout[(long long)(m0 + (ty << 2) + i) * ldc + n0 + (tx << 2) + j] = v;
    }
}

// ---------------- small fused kernels (unchanged from R1) ----------------
__global__ void bncoef(const float* __restrict__ pwb, const float* __restrict__ g,
                       const float* __restrict__ bt, const float* __restrict__ mn,
                       const float* __restrict__ vr, float* __restrict__ scl,
                       float* __restrict__ shf)
{
  const int c = threadIdx.x;
  const float inv = rsqrtf(vr[c] + 1e-5f);
  const float sc = g[c] * inv;
  scl[c] = sc;
  shf[c] = (pwb[c] - mn[c]) * sc + bt[c];
}

__global__ void uwker(const float* __restrict__ qw, const float* __restrict__ kw,
                      const float* __restrict__ r, float* __restrict__ u,
                      float* __restrict__ w)
{
  const int b = blockIdx.x, c = threadIdx.x;
  __shared__ float rl[256];
  rl[c] = r[b * C_ + c];
  __syncthreads();
  float su = 0.f, sw = 0.f;
  for (int f = 0; f < C_; ++f) {
    const float rv = rl[f];
    su = fmaf(qw[c * C_ + f], rv, su);
    sw = fmaf(kw[c * C_ + f], rv, sw);
  }
  u[b * C_ + c] = su;
  w[b * C_ + c] = sw;
}

__global__ void fixsoftmax(float* __restrict__ att, const float* __restrict__ u,
                           const float* __restrict__ w, const float* __restrict__ qb,
                           const float* __restrict__ kb)
{
  const int c = blockIdx.x, b = blockIdx.y, d = threadIdx.x;
  const long long base = ((long long)b * C_ + c) * (long long)C_;
  const float qbc = qb[c];
  float val = att[base + d] +
              0.0625f * (u[b * C_ + c] * kb[d] + qbc * w[b * C_ + d] +
                         (float)N_ * qbc * kb[d]);
  __shared__ float red[256];
  red[d] = val;
  __syncthreads();
  for (int k = 128; k > 0; k >>= 1) {
    if (d < k) red[d] = fmaxf(red[d], red[d + k]);
    __syncthreads();
  }
  const float mx = red[0];
  __syncthreads();
  const float e = expf(val - mx);
  red[d] = e;
  __syncthreads();
  for (int k = 128; k > 0; k >>= 1) {
    if (d < k) red[d] += red[d + k];
    __syncthreads();
  }
  att[base + d] = e / red[0];
}

__global__ void m2bker(const float* __restrict__ att, const float* __restrict__ vb,
                       float* __restrict__ m2b)
{
  const int b = blockIdx.x, d = threadIdx.x;
  const float* a = att + (long long)b * C_ * C_;
  float s = 0.f;
  for (int c = 0; c < C_; ++c) s = fmaf(a[c * C_ + d], vb[c], s);
  m2b[b * C_ + d] = s;
}

__global__ void b3ker(const float* __restrict__ opw, const float* __restrict__ m2b,
                      const float* __restrict__ opb, float* __restrict__ b3)
{
  const int b = blockIdx.x, o = threadIdx.x;
  __shared__ float m[256];
  m[o] = m2b[b * C_ + o];
  __syncthreads();
  float s = opb[o];
  for (int d = 0; d < C_; ++d) s = fmaf(opw[o * C_ + d], m[d], s);
  b3[b * C_ + o] = s;
}

// ===========================================================================
extern "C" void kernel_launch(void* const* d_in, const int* in_sizes, int n_in,
                              void* d_out, int out_size, void* d_ws, size_t ws_size,
                              hipStream_t stream)
{
  (void)in_sizes; (void)n_in; (void)out_size; (void)ws_size;
  const float* z     = (const float*)d_in[0];
  const float* x     = (const float*)d_in[1];
  const float* dimg  = (const float*)d_in[2];
  const float* dw_w  = (const float*)d_in[3];
  const float* dw_b  = (const float*)d_in[4];
  const float* pw_w  = (const float*)d_in[5];
  const float* pw_b  = (const float*)d_in[6];
  const float* bn_g  = (const float*)d_in[7];
  const float* bn_b  = (const float*)d_in[8];
  const float* bn_m  = (const float*)d_in[9];
  const float* bn_v  = (const float*)d_in[10];
  const float* inp_w = (const float*)d_in[11];
  const float* inp_b = (const float*)d_in[12];
  const float* q_w   = (const float*)d_in[13];
  const float* q_b   = (const float*)d_in[14];
  const float* k_w   = (const float*)d_in[15];
  const float* k_b   = (const float*)d_in[16];
  const float* v_w   = (const float*)d_in[17];
  const float* v_b   = (const float*)d_in[18];
  const float* op_w  = (const float*)d_in[19];
  const float* op_b  = (const float*)d_in[20];
  float* out = (float*)d_out;

  char* ws = (char*)d_ws;
  short* xt    = (short*)(ws + OB_XT);
  short* zt    = (short*)(ws + OB_ZT);
  short* dws   = (short*)(ws + OB_DWS);
  short* dt    = (short*)(ws + OB_DT);
  short* px_b  = (short*)(ws + OB_PX);
  short* corr  = (short*)(ws + OB_CORR);
  float* G     = (float*)(ws + OB_G);
  float* T1    = (float*)(ws + OB_T1);
  short* s_b   = (short*)(ws + OB_S);
  short* pxT   = (short*)(ws + OB_PXT);
  float* att   = (float*)(ws + OB_ATT);
  float* M2    = (float*)(ws + OB_M2);
  float* M3    = (float*)(ws + OB_M3);
  short* pw_wb = (short*)(ws + OB_PWW);
  short* inp_wb= (short*)(ws + OB_INPW);
  short* M3b   = (short*)(ws + OB_M3B);
  float* r     = (float*)(ws + OB_R);
  float* u     = (float*)(ws + OB_U);
  float* w2    = (float*)(ws + OB_W2);
  float* m2b   = (float*)(ws + OB_M2B);
  float* b3    = (float*)(ws + OB_B3);
  float* bns   = (float*)(ws + OB_BNS);
  float* bnh   = (float*)(ws + OB_BNH);

  const long long sNC = (long long)N_ * C_;
  const long long sNK = (long long)N_ * K_;
  const long long sNI = (long long)N_ * IN_;
  const long long sCC = (long long)C_ * C_;

  // --- prep: BN fold, weight casts, transpose-casts ---
  bncoef<<<1, 256, 0, stream>>>(pw_b, bn_g, bn_b, bn_m, bn_v, bns, bnh);
  castw<<<(IN_ * C_ + 255) / 256, 256, 0, stream>>>(pw_w, pw_wb, IN_ * C_);
  castw<<<(C_ * C_ + 255) / 256, 256, 0, stream>>>(inp_w, inp_wb, C_ * C_);
  tcast<<<dim3(N_ / 32, C_ / 32, B_), 256, 0, stream>>>(x, xt, C_, N_, sNC, sNC);
  tcast<<<dim3(K_ / 32, C_ / 32, B_), 256, 0, stream>>>(z, zt, C_, K_, (long long)C_ * K_,
                                                        (long long)C_ * K_);
  tcast<<<dim3(N_ / 32, C_ / 32, B_), 256, 0, stream>>>(dimg, dt, C_, N_, sNC, sNC);

  // --- corr[n,k] = sum_c xt[n,c] zt[k,c] : M=4096, BN=64, K=256, out bf16 ---
  mgemm<64, 1, 1><<<dim3(1, 32, B_), 256, 0, stream>>>(
      xt, C_, sNC, zt, C_, (long long)K_ * C_, corr, K_, sNK, C_,
      nullptr, nullptr, nullptr, nullptr, 0, 0, nullptr, 0, 0);

  // --- depthwise 3x3, output dws [n, 320] bf16 ---
  dwconv2<<<dim3(N_, B_), 320, 0, stream>>>(corr, dt, dw_w, dw_b, dws);

  // --- s[n,o] = relu(bn(sum_i dws[n,i] pw_w[o,i])) : out bf16 ---
  mgemm<128, 1, (1 | 4)><<<dim3(2, 32, B_), 256, 0, stream>>>(
      dws, IN_, sNI, pw_wb, IN_, 0, s_b, C_, sNC, IN_,
      bns, bnh, nullptr, nullptr, 0, 0, nullptr, 0, 0);

  // --- px[n,o] = sum_i s[n,i] inp_w[o,i] + inp_b : bf16 + transposed copy ---
  mgemm<128, 1, (1 | 2 | 32)><<<dim3(2, 32, B_), 256, 0, stream>>>(
      s_b, C_, sNC, inp_wb, C_, 0, px_b, C_, sNC, C_,
      inp_b, nullptr, nullptr, nullptr, 0, 0, pxT, N_, sNC);

  // --- r[b,c] = column sums of px ---
  hipMemsetAsync(r, 0, B_ * C_ * sizeof(float), stream);
  colsum<<<dim3(8, B_), 256, 0, stream>>>(px_b, r);

  // --- G = pxT @ pxT^T (K=4096, split-K=8, fp32 atomics) ---
  hipMemsetAsync(G, 0, (size_t)B_ * C_ * C_ * sizeof(float), stream);
  mgemm<128, 8, 64><<<dim3(2, 2, B_ * 8), 256, 0, stream>>>(
      pxT, N_, sNC, pxT, N_, sNC, G, C_, sCC, N_ / 8,
      nullptr, nullptr, nullptr, nullptr, 0, 0, nullptr, 0, 0);

  // --- rank-1 pieces ---
  uwker<<<B_, 256, 0, stream>>>(q_w, k_w, r, u, w2);

  // --- T1 = q_w @ G ; score = (1/16) T1 @ k_w^T (fp32 small GEMMs) ---
  gemm64<0, 0, 0><<<dim3(C_ / 64, C_ / 64, B_), 256, 0, stream>>>(
      q_w, C_, 0, G, C_, sCC, T1, C_, sCC, C_, 1.f);
  gemm64<0, 1, 8><<<dim3(C_ / 64, C_ / 64, B_), 256, 0, stream>>>(
      T1, C_, sCC, k_w, C_, 0, att, C_, sCC, C_, 0.0625f);

  fixsoftmax<<<dim3(C_, B_), 256, 0, stream>>>(att, u, w2, q_b, k_b);

  // --- M2 = att^T @ v_w ; M3 = op_w @ M2 ---
  gemm64<1, 0, 0><<<dim3(C_ / 64, C_ / 64, B_), 256, 0, stream>>>(
      att, C_, sCC, v_w, C_, 0, M2, C_, sCC, C_, 1.f);
  m2bker<<<B_, 256, 0, stream>>>(att, v_b, m2b);
  gemm64<0, 0, 0><<<dim3(C_ / 64, C_ / 64, B_), 256, 0, stream>>>(
      op_w, C_, 0, M2, C_, sCC, M3, C_, sCC, C_, 1.f);
  b3ker<<<B_, 256, 0, stream>>>(op_w, m2b, op_b, b3);
  castw<<<((int)(B_ * sCC) + 255) / 256, 256, 0, stream>>>(M3, M3b, B_ * sCC);

  // --- out[o,n] = sum_c M3[o,c] px[n,c] + b3[b,o] + s[n,o] : fp32, [b,c,h,w] ---
  mgemm<128, 1, (8 | 16)><<<dim3(32, 2, B_), 256, 0, stream>>>(
      M3b, C_, sCC, px_b, C_, sNC, out, N_, sNC, C_,
      nullptr, nullptr, b3, s_b, C_, sNC, nullptr, 0, 0);
}